// Round 7
// baseline (1610.614 us; speedup 1.0000x reference)
//
#include <hip/hip_runtime.h>

typedef unsigned short u16;
typedef __attribute__((ext_vector_type(4))) unsigned short u16x4;
typedef __attribute__((ext_vector_type(8))) unsigned short u16x8;
typedef __attribute__((ext_vector_type(8))) short s16x8;
typedef __attribute__((ext_vector_type(4))) float f32x4;

#define BATCH 16384
#define NFEAT 32
#define NVOCAB 50000
#define NBLK 512

__device__ __forceinline__ u16 f2bf(float f) {
    union { float f; unsigned u; } v; v.f = f;
    unsigned u = v.u;
    return (u16)((u + 0x7fffu + ((u >> 16) & 1u)) >> 16);
}
__device__ __forceinline__ float bf2f(u16 h) {
    union { unsigned u; float f; } v; v.u = ((unsigned)h) << 16;
    return v.f;
}
__device__ __forceinline__ void load_lds16(const u16* g, u16* l) {
    __builtin_amdgcn_global_load_lds(
        (const __attribute__((address_space(1))) void*)g,
        (__attribute__((address_space(3))) void*)l, 16, 0, 0);
}

// Manual grid barrier: monotonic arrival counter + generation counter.
// Requires all NBLK blocks co-resident (capacity: 2 blocks/CU x 256 CUs).
__device__ __forceinline__ void grid_sync(unsigned* cnt, unsigned* gen) {
    __syncthreads();                       // drains vmcnt (all stores issued)
    if (threadIdx.x == 0) {
        __threadfence();                   // agent release: L2 writeback (cross-XCD)
        unsigned arrival = __hip_atomic_fetch_add(cnt, 1u, __ATOMIC_ACQ_REL,
                                                  __HIP_MEMORY_SCOPE_AGENT) + 1u;
        unsigned target = (arrival + NBLK - 1u) / NBLK;
        if (arrival % NBLK == 0u)
            __hip_atomic_fetch_add(gen, 1u, __ATOMIC_ACQ_REL,
                                   __HIP_MEMORY_SCOPE_AGENT);
        while (__hip_atomic_load(gen, __ATOMIC_ACQUIRE,
                                 __HIP_MEMORY_SCOPE_AGENT) < target)
            __builtin_amdgcn_s_sleep(1);
        __threadfence();                   // agent acquire: invalidate stale lines
    }
    __syncthreads();
}

struct MonoArgs {
    const int* x_ids; const float* emb;
    const float* e1W1; const float* e1b1; const float* e1W2; const float* e1b2;
    const float* g1Ws; const float* g1bs; const float* g1Wsh; const float* g1bsh;
    const float* e2W1; const float* e2b1; const float* e2W2; const float* e2b2;
    const float* g2Ws; const float* g2bs;
    const float* twW1; const float* twb1; const float* twW2; const float* twb2;
    u16* embed; u16* wt_e1W1; u16* wt_e1W2; u16* wt_e2W1; u16* wt_e2W2;
    u16* wt_twW1; u16* wt_twW2; u16* h_buf; u16* o_buf; u16* x1; u16* x2;
    unsigned* bar;
    float* out;
};

// ---------------------------------------------------------------------------
// GEMM tile core (r4-verified): C tile = relu(A[128,K] @ B[256,K]^T + bias)
// ---------------------------------------------------------------------------
__device__ __forceinline__ void gemm_core(const u16* __restrict__ Ab,
                                          const u16* __restrict__ Bb,
                                          const float* __restrict__ bb,
                                          u16* __restrict__ Cp,
                                          int N, int K, int m0, int n0,
                                          char* smem) {
    u16* sA = (u16*)smem;
    u16* sB = (u16*)(smem + 16384);
    const int tid = threadIdx.x;
    const int lane = tid & 63;
    const int w = tid >> 6;
    const int wm = (w & 1) * 64;
    const int wn = (w >> 1) * 128;
    const int l16 = lane & 15;
    const int q = lane >> 4;
    const int key = l16 & 7;

    const int tr = tid >> 3;
    const int lc = (tid & 7) ^ (tr & 7);
    const u16* gA0 = Ab + (long)(m0 + tr) * K + lc * 8;
    const u16* gB0 = Bb + (long)(n0 + tr) * K + lc * 8;
    u16* lA0 = &sA[(tid & ~63) * 8];
    u16* lB0 = &sB[(tid & ~63) * 8];

    f32x4 acc[4][8] = {};

    for (int k0 = 0; k0 < K; k0 += 64) {
        if (k0) __syncthreads();
        #pragma unroll
        for (int i = 0; i < 4; i++)
            load_lds16(gA0 + (long)(32 * i) * K + k0, lA0 + i * 256 * 8);
        #pragma unroll
        for (int i = 0; i < 8; i++)
            load_lds16(gB0 + (long)(32 * i) * K + k0, lB0 + i * 256 * 8);
        __syncthreads();
        #pragma unroll
        for (int kk = 0; kk < 2; kk++) {
            const int pc = ((kk << 2) | q) ^ key;
            s16x8 af[4], bf[8];
            #pragma unroll
            for (int mt = 0; mt < 4; mt++)
                af[mt] = *(const s16x8*)(&sA[(wm + mt * 16 + l16) * 64 + pc * 8]);
            #pragma unroll
            for (int nt = 0; nt < 8; nt++)
                bf[nt] = *(const s16x8*)(&sB[(wn + nt * 16 + l16) * 64 + pc * 8]);
            #pragma unroll
            for (int mt = 0; mt < 4; mt++)
                #pragma unroll
                for (int nt = 0; nt < 8; nt++)
                    acc[mt][nt] = __builtin_amdgcn_mfma_f32_16x16x32_bf16(
                        bf[nt], af[mt], acc[mt][nt], 0, 0, 0);
        }
    }

    #pragma unroll
    for (int mt = 0; mt < 4; mt++) {
        int grow = m0 + wm + mt * 16 + l16;
        u16* rowp = Cp + (long)grow * N;
        #pragma unroll
        for (int nt = 0; nt < 8; nt++) {
            int gc = n0 + wn + nt * 16 + q * 4;
            float4 bv = *(const float4*)(bb + gc);
            f32x4 v = acc[mt][nt];
            v.x = fmaxf(v.x + bv.x, 0.f);
            v.y = fmaxf(v.y + bv.y, 0.f);
            v.z = fmaxf(v.z + bv.z, 0.f);
            v.w = fmaxf(v.w + bv.w, 0.f);
            u16x4 o;
            o.x = f2bf(v.x); o.y = f2bf(v.y); o.z = f2bf(v.z); o.w = f2bf(v.w);
            *(u16x4*)(rowp + gc) = o;
        }
    }
}

__device__ void gemm_phase(const u16* A, long a_zstride, int a_zshift,
                           const u16* Bt, const float* bias, u16* C,
                           int N, int K, char* smem) {
    const int ny = N >> 8;
    const int per_m = ny * 6;
    const int njobs = 128 * per_m;
    for (int job = blockIdx.x; job < njobs; job += NBLK) {
        int m0 = (job / per_m) * 128;
        int rem = job % per_m;
        int z = rem / ny;
        int n0 = (rem % ny) * 256;
        __syncthreads();
        gemm_core(A + (long)(z >> a_zshift) * a_zstride,
                  Bt + (long)z * N * K,
                  bias + (long)z * N,
                  C + (long)z * BATCH * N,
                  N, K, m0, n0, smem);
    }
}

// ---------------------------------------------------------------------------
__global__ __launch_bounds__(256, 2)
void mono(MonoArgs a) {
    __shared__ __align__(16) char smem[49152];
    unsigned* bcnt = a.bar;
    unsigned* bgen = a.bar + 16;
    const int tid = threadIdx.x;
    const int lane = tid & 63, w4 = tid >> 6;
    const int l16 = lane & 15, q = lane >> 4;

    // ===== P0: embedding gather (blocks 0..255) + weight prep (256..511) ====
    if (blockIdx.x < 256) {
        for (long idx = (long)blockIdx.x * 256 + tid; idx < (long)BATCH * NFEAT * 4;
             idx += 65536) {
            int d4 = (int)(idx & 3);
            int f  = (int)((idx >> 2) & 31);
            int b  = (int)(idx >> 7);
            int id = a.x_ids[b * NFEAT + f];
            float4 v = *((const float4*)(a.emb + ((long)f * NVOCAB + id) * 16) + d4);
            u16x4 o;
            o.x = f2bf(v.x); o.y = f2bf(v.y); o.z = f2bf(v.z); o.w = f2bf(v.w);
            *(u16x4*)(a.embed + (long)b * 512 + f * 16 + d4 * 4) = o;
        }
    } else {
        float* tile = (float*)smem;      // [32][33]
        const int tx = tid & 31, ty = tid >> 5;
        for (int j = blockIdx.x - 256; j < 7168; j += 256) {
            int z = j >> 8;
            int rem = j & 255;
            const float* src; u16* dst; int K, N, zb;
            if      (z <  6) { src = a.e1W1; dst = a.wt_e1W1; K = 512; N = 512; zb = 0; }
            else if (z < 12) { src = a.e1W2; dst = a.wt_e1W2; K = 512; N = 256; zb = 6; }
            else if (z < 18) { src = a.e2W1; dst = a.wt_e2W1; K = 256; N = 512; zb = 12; }
            else if (z < 24) { src = a.e2W2; dst = a.wt_e2W2; K = 512; N = 256; zb = 18; }
            else if (z < 26) { src = a.twW1; dst = a.wt_twW1; K = 256; N = 128; zb = 24; }
            else             { src = a.twW2; dst = a.wt_twW2; K = 128; N = 64;  zb = 26; }
            int zz = z - zb;
            int k0 = (rem & 15) * 32, n0 = (rem >> 4) * 32;
            if (k0 >= K || n0 >= N) continue;
            __syncthreads();
            const float* s = src + (long)zz * K * N;
            u16* d = dst + (long)zz * K * N;
            for (int r = ty; r < 32; r += 8) {
                int k = k0 + r, n = n0 + tx;
                tile[r * 33 + tx] = (k < K && n < N) ? s[(long)k * N + n] : 0.f;
            }
            __syncthreads();
            for (int r = ty; r < 32; r += 8) {
                int n = n0 + r, k = k0 + tx;
                if (n < N && k < K) d[(long)n * K + k] = f2bf(tile[tx * 33 + r]);
            }
        }
    }
    grid_sync(bcnt, bgen);

    // ===== P1: level-1 expert layer 1: h_buf = relu(embed @ W1) ====
    gemm_phase(a.embed, 0L, 3, a.wt_e1W1, a.e1b1, a.h_buf, 512, 512, smem);
    grid_sync(bcnt, bgen);

    // ===== P2: level-1 expert layer 2: o_buf = relu(h_buf @ W2) ====
    gemm_phase(a.h_buf, (long)BATCH * 512, 0, a.wt_e1W2, a.e1b2, a.o_buf, 256, 512, smem);
    grid_sync(bcnt, bgen);

    // ===== P3: gate1 -> x1 ====
    {
        float (*sg)[16] = (float(*)[16])smem;
        const int row = tid >> 5, l = tid & 31;
        for (int job = blockIdx.x; job < 2048; job += NBLK) {
            const long rb = (long)job * 8 + row;
            float ga[4] = {0,0,0,0}, gb[4] = {0,0,0,0}, gc[6] = {0,0,0,0,0,0};
            {
                const u16* er = a.embed + rb * 512 + l * 16;
                u16x8 xa = *(const u16x8*)(er);
                u16x8 xb = *(const u16x8*)(er + 8);
                #pragma unroll
                for (int u = 0; u < 16; u++) {
                    int k = l * 16 + u;
                    float xv = bf2f(u < 8 ? xa[u] : xb[u - 8]);
                    float4 wa = *(const float4*)(a.g1Ws + k * 4);
                    float4 wb = *(const float4*)(a.g1Ws + 2048 + k * 4);
                    ga[0] += xv * wa.x; ga[1] += xv * wa.y; ga[2] += xv * wa.z; ga[3] += xv * wa.w;
                    gb[0] += xv * wb.x; gb[1] += xv * wb.y; gb[2] += xv * wb.z; gb[3] += xv * wb.w;
                    float2 w0 = *(const float2*)(a.g1Wsh + k * 6);
                    float2 w1 = *(const float2*)(a.g1Wsh + k * 6 + 2);
                    float2 w2 = *(const float2*)(a.g1Wsh + k * 6 + 4);
                    gc[0] += xv * w0.x; gc[1] += xv * w0.y;
                    gc[2] += xv * w1.x; gc[3] += xv * w1.y;
                    gc[4] += xv * w2.x; gc[5] += xv * w2.y;
                }
            }
            #pragma unroll
            for (int off = 1; off < 32; off <<= 1) {
                #pragma unroll
                for (int g = 0; g < 4; g++) { ga[g] += __shfl_xor(ga[g], off); gb[g] += __shfl_xor(gb[g], off); }
                #pragma unroll
                for (int g = 0; g < 6; g++) gc[g] += __shfl_xor(gc[g], off);
            }
            if (l == 0) {
                float mx, s, e[6];
                mx = -1e30f;
                for (int g = 0; g < 4; g++) { ga[g] += a.g1bs[g]; mx = fmaxf(mx, ga[g]); }
                s = 0.f; for (int g = 0; g < 4; g++) { e[g] = __expf(ga[g] - mx); s += e[g]; }
                for (int g = 0; g < 4; g++) sg[row][g] = e[g] / s;
                mx = -1e30f;
                for (int g = 0; g < 4; g++) { gb[g] += a.g1bs[4 + g]; mx = fmaxf(mx, gb[g]); }
                s = 0.f; for (int g = 0; g < 4; g++) { e[g] = __expf(gb[g] - mx); s += e[g]; }
                for (int g = 0; g < 4; g++) sg[row][4 + g] = e[g] / s;
                mx = -1e30f;
                for (int g = 0; g < 6; g++) { gc[g] += a.g1bsh[g]; mx = fmaxf(mx, gc[g]); }
                s = 0.f; for (int g = 0; g < 6; g++) { e[g] = __expf(gc[g] - mx); s += e[g]; }
                for (int g = 0; g < 6; g++) sg[row][8 + g] = e[g] / s;
            }
            __syncthreads();
            const int c8 = l * 8;
            const u16* ob = a.o_buf + rb * 256 + c8;
            u16x8 o[6];
            #pragma unroll
            for (int k = 0; k < 6; k++) o[k] = *(const u16x8*)(ob + (long)k * BATCH * 256);
            const float* g = sg[row];
            u16x8 r0, r1, r2;
            #pragma unroll
            for (int u = 0; u < 8; u++) {
                float o0 = bf2f(o[0][u]), o1 = bf2f(o[1][u]), o2 = bf2f(o[2][u]);
                float o3 = bf2f(o[3][u]), o4 = bf2f(o[4][u]), o5 = bf2f(o[5][u]);
                r0[u] = f2bf(g[0] * o0 + g[1] * o1 + g[2] * o4 + g[3] * o5);
                r1[u] = f2bf(g[4] * o2 + g[5] * o3 + g[6] * o4 + g[7] * o5);
                r2[u] = f2bf(g[8] * o0 + g[9] * o1 + g[10] * o2 + g[11] * o3 + g[12] * o4 + g[13] * o5);
            }
            *(u16x8*)(a.x1 + ((long)0 * BATCH + rb) * 256 + c8) = r0;
            *(u16x8*)(a.x1 + ((long)1 * BATCH + rb) * 256 + c8) = r1;
            *(u16x8*)(a.x1 + ((long)2 * BATCH + rb) * 256 + c8) = r2;
            __syncthreads();
        }
    }
    grid_sync(bcnt, bgen);

    // ===== P4: level-2 expert layer 1 ====
    gemm_phase(a.x1, (long)BATCH * 256, 1, a.wt_e2W1, a.e2b1, a.h_buf, 512, 256, smem);
    grid_sync(bcnt, bgen);

    // ===== P5: level-2 expert layer 2 ====
    gemm_phase(a.h_buf, (long)BATCH * 512, 0, a.wt_e2W2, a.e2b2, a.o_buf, 256, 512, smem);
    grid_sync(bcnt, bgen);

    // ===== P6: gate2 -> x2 ====
    {
        float (*sg)[8] = (float(*)[8])smem;
        const int row = tid >> 5, l = tid & 31;
        for (int job = blockIdx.x; job < 2048; job += NBLK) {
            const long rb = (long)job * 8 + row;
            float ga[4] = {0,0,0,0}, gb[4] = {0,0,0,0};
            {
                const u16* e0 = a.x1 + rb * 256 + l * 8;
                const u16* e1 = e0 + (long)BATCH * 256;
                u16x8 x0 = *(const u16x8*)e0;
                u16x8 x1v = *(const u16x8*)e1;
                #pragma unroll
                for (int u = 0; u < 8; u++) {
                    int k = l * 8 + u;
                    float4 wa = *(const float4*)(a.g2Ws + k * 4);
                    float4 wb = *(const float4*)(a.g2Ws + 1024 + k * 4);
                    float xv0 = bf2f(x0[u]), xv1 = bf2f(x1v[u]);
                    ga[0] += xv0 * wa.x; ga[1] += xv0 * wa.y; ga[2] += xv0 * wa.z; ga[3] += xv0 * wa.w;
                    gb[0] += xv1 * wb.x; gb[1] += xv1 * wb.y; gb[2] += xv1 * wb.z; gb[3] += xv1 * wb.w;
                }
            }
            #pragma unroll
            for (int off = 1; off < 32; off <<= 1) {
                #pragma unroll
                for (int g = 0; g < 4; g++) { ga[g] += __shfl_xor(ga[g], off); gb[g] += __shfl_xor(gb[g], off); }
            }
            if (l == 0) {
                float mx, s, e[4];
                mx = -1e30f;
                for (int g = 0; g < 4; g++) { ga[g] += a.g2bs[g]; mx = fmaxf(mx, ga[g]); }
                s = 0.f; for (int g = 0; g < 4; g++) { e[g] = __expf(ga[g] - mx); s += e[g]; }
                for (int g = 0; g < 4; g++) sg[row][g] = e[g] / s;
                mx = -1e30f;
                for (int g = 0; g < 4; g++) { gb[g] += a.g2bs[4 + g]; mx = fmaxf(mx, gb[g]); }
                s = 0.f; for (int g = 0; g < 4; g++) { e[g] = __expf(gb[g] - mx); s += e[g]; }
                for (int g = 0; g < 4; g++) sg[row][4 + g] = e[g] / s;
            }
            __syncthreads();
            const int c8 = l * 8;
            const u16* ob = a.o_buf + rb * 256 + c8;
            u16x8 o[6];
            #pragma unroll
            for (int k = 0; k < 6; k++) o[k] = *(const u16x8*)(ob + (long)k * BATCH * 256);
            const float* g = sg[row];
            u16x8 r0, r1;
            #pragma unroll
            for (int u = 0; u < 8; u++) {
                float o0 = bf2f(o[0][u]), o1 = bf2f(o[1][u]), o2 = bf2f(o[2][u]);
                float o3 = bf2f(o[3][u]), o4 = bf2f(o[4][u]), o5 = bf2f(o[5][u]);
                r0[u] = f2bf(g[0] * o0 + g[1] * o1 + g[2] * o4 + g[3] * o5);
                r1[u] = f2bf(g[4] * o2 + g[5] * o3 + g[6] * o4 + g[7] * o5);
            }
            *(u16x8*)(a.x2 + ((long)0 * BATCH + rb) * 256 + c8) = r0;
            *(u16x8*)(a.x2 + ((long)1 * BATCH + rb) * 256 + c8) = r1;
            __syncthreads();
        }
    }
    grid_sync(bcnt, bgen);

    // ===== P7: towers -> out ====
    {
        u16* sX = (u16*)smem;                  // 64x256 swizzled
        u16* sH = (u16*)(smem + 32768);        // 64x128 swizzled
        for (int job = blockIdx.x; job < 512; job += NBLK) {
            int t = job >> 8;
            int m0 = (job & 255) * 64;
            const u16* W1 = a.wt_twW1 + (long)t * 128 * 256;
            const u16* W2 = a.wt_twW2 + (long)t * 64 * 128;
            __syncthreads();
            #pragma unroll
            for (int i = 0; i < 8; i++) {
                int p = i * 256 + tid, row = p >> 5, pcc = p & 31;
                int c = (pcc & ~7) | ((pcc & 7) ^ (row & 7));
                load_lds16(a.x2 + ((long)t * BATCH + m0 + row) * 256 + c * 8,
                           sX + (i * 256 + (tid & ~63)) * 8);
            }
            __syncthreads();
            f32x4 acc1[4][2] = {};
            #pragma unroll
            for (int kk = 0; kk < 8; kk++) {
                s16x8 af[4], bf[2];
                #pragma unroll
                for (int nt = 0; nt < 2; nt++) {
                    int nrow = w4 * 32 + nt * 16 + l16;
                    bf[nt] = *(const s16x8*)(W1 + (long)nrow * 256 + kk * 32 + q * 8);
                }
                #pragma unroll
                for (int mt = 0; mt < 4; mt++) {
                    int row = mt * 16 + l16;
                    int cc = kk * 4 + q;
                    int pc = (cc & ~7) | ((cc & 7) ^ (row & 7));
                    af[mt] = *(const s16x8*)(&sX[row * 256 + pc * 8]);
                }
                #pragma unroll
                for (int mt = 0; mt < 4; mt++)
                    #pragma unroll
                    for (int nt = 0; nt < 2; nt++)
                        acc1[mt][nt] = __builtin_amdgcn_mfma_f32_16x16x32_bf16(
                            bf[nt], af[mt], acc1[mt][nt], 0, 0, 0);
            }
            #pragma unroll
            for (int mt = 0; mt < 4; mt++) {
                int row = mt * 16 + l16;
                #pragma unroll
                for (int nt = 0; nt < 2; nt++) {
                    int col = w4 * 32 + nt * 16 + q * 4;
                    float4 bv = *(const float4*)(a.twb1 + t * 128 + col);
                    f32x4 v = acc1[mt][nt];
                    u16x4 o;
                    o.x = f2bf(fmaxf(v.x + bv.x, 0.f));
                    o.y = f2bf(fmaxf(v.y + bv.y, 0.f));
                    o.z = f2bf(fmaxf(v.z + bv.z, 0.f));
                    o.w = f2bf(fmaxf(v.w + bv.w, 0.f));
                    int c = col >> 3;
                    int pc = (c & ~7) | ((c & 7) ^ (row & 7));
                    *(u16x4*)(&sH[row * 128 + pc * 8 + (col & 7)]) = o;
                }
            }
            __syncthreads();
            f32x4 acc2[4] = {};
            #pragma unroll
            for (int kk = 0; kk < 4; kk++) {
                s16x8 af[4], bfv;
                {
                    int nrow = w4 * 16 + l16;
                    bfv = *(const s16x8*)(W2 + (long)nrow * 128 + kk * 32 + q * 8);
                }
                #pragma unroll
                for (int mt = 0; mt < 4; mt++) {
                    int row = mt * 16 + l16;
                    int cc = kk * 4 + q;
                    int pc = (cc & ~7) | ((cc & 7) ^ (row & 7));
                    af[mt] = *(const s16x8*)(&sH[row * 128 + pc * 8]);
                }
                #pragma unroll
                for (int mt = 0; mt < 4; mt++)
                    acc2[mt] = __builtin_amdgcn_mfma_f32_16x16x32_bf16(
                        bfv, af[mt], acc2[mt], 0, 0, 0);
            }
            #pragma unroll
            for (int mt = 0; mt < 4; mt++) {
                int grow = m0 + mt * 16 + l16;
                int col = w4 * 16 + q * 4;
                float4 bv = *(const float4*)(a.twb2 + t * 64 + col);
                f32x4 v = acc2[mt];
                float4 r;
                r.x = 1.f / (1.f + __expf(-(v.x + bv.x)));
                r.y = 1.f / (1.f + __expf(-(v.y + bv.y)));
                r.z = 1.f / (1.f + __expf(-(v.z + bv.z)));
                r.w = 1.f / (1.f + __expf(-(v.w + bv.w)));
                *(float4*)(a.out + (long)grow * 128 + t * 64 + col) = r;
            }
        }
    }
}

// ---------------------------------------------------------------------------
extern "C" void kernel_launch(void* const* d_in, const int* in_sizes, int n_in,
                              void* d_out, int out_size, void* d_ws, size_t ws_size,
                              hipStream_t stream) {
    char* ws = (char*)d_ws;
    MonoArgs a;
    a.x_ids = (const int*)  d_in[0];
    a.emb   = (const float*)d_in[1];
    a.e1W1  = (const float*)d_in[2];
    a.e1b1  = (const float*)d_in[3];
    a.e1W2  = (const float*)d_in[4];
    a.e1b2  = (const float*)d_in[5];
    a.g1Ws  = (const float*)d_in[6];
    a.g1bs  = (const float*)d_in[7];
    a.g1Wsh = (const float*)d_in[8];
    a.g1bsh = (const float*)d_in[9];
    a.e2W1  = (const float*)d_in[10];
    a.e2b1  = (const float*)d_in[11];
    a.e2W2  = (const float*)d_in[12];
    a.e2b2  = (const float*)d_in[13];
    a.g2Ws  = (const float*)d_in[14];
    a.g2bs  = (const float*)d_in[15];
    a.twW1  = (const float*)d_in[16];
    a.twb1  = (const float*)d_in[17];
    a.twW2  = (const float*)d_in[18];
    a.twb2  = (const float*)d_in[19];
    a.embed   = (u16*)(ws + 0);
    a.wt_e1W1 = (u16*)(ws + 16777216);
    a.wt_e1W2 = (u16*)(ws + 19922944);
    a.wt_e2W1 = (u16*)(ws + 21495808);
    a.wt_e2W2 = (u16*)(ws + 23068672);
    a.wt_twW1 = (u16*)(ws + 24641536);
    a.wt_twW2 = (u16*)(ws + 24772608);
    a.h_buf   = (u16*)(ws + 24805376);
    a.o_buf   = (u16*)(ws + 125468672);
    a.x1      = (u16*)(ws + 175800320);
    a.x2      = (u16*)(ws + 200966144);
    a.bar     = (unsigned*)(ws + 218103808);
    a.out     = (float*)d_out;

    // zero the barrier counters (cnt at +0, gen at +64 bytes)
    hipMemsetAsync((void*)a.bar, 0, 128, stream);
    mono<<<dim3(NBLK), dim3(256), 0, stream>>>(a);
}

// Round 8
// 557.537 us; speedup vs baseline: 2.8888x; 2.8888x over previous
//
#include <hip/hip_runtime.h>

typedef unsigned short u16;
typedef __attribute__((ext_vector_type(4))) unsigned short u16x4;
typedef __attribute__((ext_vector_type(8))) unsigned short u16x8;
typedef __attribute__((ext_vector_type(8))) short s16x8;
typedef __attribute__((ext_vector_type(4))) float f32x4;

#define BATCH 16384
#define NFEAT 32
#define NVOCAB 50000

__device__ __forceinline__ u16 f2bf(float f) {
    union { float f; unsigned u; } v; v.f = f;
    unsigned u = v.u;
    return (u16)((u + 0x7fffu + ((u >> 16) & 1u)) >> 16);
}
__device__ __forceinline__ float bf2f(u16 h) {
    union { unsigned u; float f; } v; v.u = ((unsigned)h) << 16;
    return v.f;
}
__device__ __forceinline__ void load_lds16(const u16* g, u16* l) {
    __builtin_amdgcn_global_load_lds(
        (const __attribute__((address_space(1))) void*)g,
        (__attribute__((address_space(3))) void*)l, 16, 0, 0);
}

// ---------------------------------------------------------------------------
// P0: embedding gather (blocks 0..255) + weight transpose/cast (blocks 256..511)
// (body verified inside r7 mono)
// ---------------------------------------------------------------------------
struct P0Args {
    const int* x_ids; const float* emb;
    const float* e1W1; const float* e1W2; const float* e2W1; const float* e2W2;
    const float* twW1; const float* twW2;
    u16* embed; u16* wt_e1W1; u16* wt_e1W2; u16* wt_e2W1; u16* wt_e2W2;
    u16* wt_twW1; u16* wt_twW2;
};

__global__ __launch_bounds__(256)
void p0_gather_prep(P0Args a) {
    __shared__ float tile[32 * 33];
    const int tid = threadIdx.x;
    if (blockIdx.x < 256) {
        for (long idx = (long)blockIdx.x * 256 + tid; idx < (long)BATCH * NFEAT * 4;
             idx += 65536) {
            int d4 = (int)(idx & 3);
            int f  = (int)((idx >> 2) & 31);
            int b  = (int)(idx >> 7);
            int id = a.x_ids[b * NFEAT + f];
            float4 v = *((const float4*)(a.emb + ((long)f * NVOCAB + id) * 16) + d4);
            u16x4 o;
            o.x = f2bf(v.x); o.y = f2bf(v.y); o.z = f2bf(v.z); o.w = f2bf(v.w);
            *(u16x4*)(a.embed + (long)b * 512 + f * 16 + d4 * 4) = o;
        }
    } else {
        const int tx = tid & 31, ty = tid >> 5;
        for (int j = blockIdx.x - 256; j < 7168; j += 256) {
            int z = j >> 8;
            int rem = j & 255;
            const float* src; u16* dst; int K, N, zb;
            if      (z <  6) { src = a.e1W1; dst = a.wt_e1W1; K = 512; N = 512; zb = 0; }
            else if (z < 12) { src = a.e1W2; dst = a.wt_e1W2; K = 512; N = 256; zb = 6; }
            else if (z < 18) { src = a.e2W1; dst = a.wt_e2W1; K = 256; N = 512; zb = 12; }
            else if (z < 24) { src = a.e2W2; dst = a.wt_e2W2; K = 512; N = 256; zb = 18; }
            else if (z < 26) { src = a.twW1; dst = a.wt_twW1; K = 256; N = 128; zb = 24; }
            else             { src = a.twW2; dst = a.wt_twW2; K = 128; N = 64;  zb = 26; }
            int zz = z - zb;
            int k0 = (rem & 15) * 32, n0 = (rem >> 4) * 32;
            if (k0 >= K || n0 >= N) continue;
            __syncthreads();
            const float* s = src + (long)zz * K * N;
            u16* d = dst + (long)zz * K * N;
            for (int r = ty; r < 32; r += 8) {
                int k = k0 + r, n = n0 + tx;
                tile[r * 33 + tx] = (k < K && n < N) ? s[(long)k * N + n] : 0.f;
            }
            __syncthreads();
            for (int r = ty; r < 32; r += 8) {
                int n = n0 + r, k = k0 + tx;
                if (n < N && k < K) d[(long)n * K + k] = f2bf(tile[tx * 33 + r]);
            }
        }
    }
}

// ---------------------------------------------------------------------------
// Batched GEMM (r4-verified): C[z] = relu(A[z>>a_zshift] @ Bt[z]^T + bias[z])
// Block tile 128x256, 4 waves of 64x128, BK=64, mfma 16x16x32 (swapped ops),
// global_load_lds dwordx4 staging with XOR source swizzle.
// ---------------------------------------------------------------------------
struct GemmP {
    const u16* A; const u16* Bt; const float* bias; u16* C;
    int N, K, a_zshift, c_row_stride; long a_zstride, c_zstride;
};

__device__ __forceinline__ void gemm_impl(const GemmP p) {
    __shared__ u16 sA[128 * 64];
    __shared__ u16 sB[256 * 64];
    const int z = blockIdx.z;
    const u16* Ab = p.A + (long)(z >> p.a_zshift) * p.a_zstride;
    const u16* Bb = p.Bt + (long)z * p.N * p.K;
    const int m0 = blockIdx.x * 128;
    const int n0 = blockIdx.y * 256;
    const int tid = threadIdx.x;
    const int lane = tid & 63;
    const int w = tid >> 6;
    const int wm = (w & 1) * 64;
    const int wn = (w >> 1) * 128;
    const int l16 = lane & 15;
    const int q = lane >> 4;
    const int key = l16 & 7;
    const int K = p.K;

    const int tr = tid >> 3;
    const int lc = (tid & 7) ^ (tr & 7);
    const u16* gA0 = Ab + (long)(m0 + tr) * K + lc * 8;
    const u16* gB0 = Bb + (long)(n0 + tr) * K + lc * 8;
    u16* lA0 = &sA[(tid & ~63) * 8];
    u16* lB0 = &sB[(tid & ~63) * 8];

    f32x4 acc[4][8] = {};

    for (int k0 = 0; k0 < K; k0 += 64) {
        if (k0) __syncthreads();
        #pragma unroll
        for (int i = 0; i < 4; i++)
            load_lds16(gA0 + (long)(32 * i) * K + k0, lA0 + i * 256 * 8);
        #pragma unroll
        for (int i = 0; i < 8; i++)
            load_lds16(gB0 + (long)(32 * i) * K + k0, lB0 + i * 256 * 8);
        __syncthreads();
        #pragma unroll
        for (int kk = 0; kk < 2; kk++) {
            const int pc = ((kk << 2) | q) ^ key;
            s16x8 af[4], bf[8];
            #pragma unroll
            for (int mt = 0; mt < 4; mt++)
                af[mt] = *(const s16x8*)(&sA[(wm + mt * 16 + l16) * 64 + pc * 8]);
            #pragma unroll
            for (int nt = 0; nt < 8; nt++)
                bf[nt] = *(const s16x8*)(&sB[(wn + nt * 16 + l16) * 64 + pc * 8]);
            #pragma unroll
            for (int mt = 0; mt < 4; mt++)
                #pragma unroll
                for (int nt = 0; nt < 8; nt++)
                    acc[mt][nt] = __builtin_amdgcn_mfma_f32_16x16x32_bf16(
                        bf[nt], af[mt], acc[mt][nt], 0, 0, 0);
        }
    }

    const float* bb = p.bias + (long)z * p.N;
    u16* Cp = p.C + (long)z * p.c_zstride;
    #pragma unroll
    for (int mt = 0; mt < 4; mt++) {
        int grow = m0 + wm + mt * 16 + l16;
        u16* rowp = Cp + (long)grow * p.c_row_stride;
        #pragma unroll
        for (int nt = 0; nt < 8; nt++) {
            int gc = n0 + wn + nt * 16 + q * 4;
            float4 bv = *(const float4*)(bb + gc);
            f32x4 v = acc[mt][nt];
            v.x = fmaxf(v.x + bv.x, 0.f);
            v.y = fmaxf(v.y + bv.y, 0.f);
            v.z = fmaxf(v.z + bv.z, 0.f);
            v.w = fmaxf(v.w + bv.w, 0.f);
            u16x4 o;
            o.x = f2bf(v.x); o.y = f2bf(v.y); o.z = f2bf(v.z); o.w = f2bf(v.w);
            *(u16x4*)(rowp + gc) = o;
        }
    }
}

__global__ __launch_bounds__(256, 2) void gemm_l1a(GemmP p) { gemm_impl(p); }
__global__ __launch_bounds__(256, 2) void gemm_l1b(GemmP p) { gemm_impl(p); }
__global__ __launch_bounds__(256, 2) void gemm_l2a(GemmP p) { gemm_impl(p); }
__global__ __launch_bounds__(256, 2) void gemm_l2b(GemmP p) { gemm_impl(p); }

// ---------------------------------------------------------------------------
// Level-1 fused gates+combine (r4-verified): 8 rows/block, 2048 blocks
// ---------------------------------------------------------------------------
__global__ __launch_bounds__(256)
void gate1(const u16* __restrict__ embed, const u16* __restrict__ out1,
           const float* __restrict__ g1Ws, const float* __restrict__ g1bs,
           const float* __restrict__ gWsh, const float* __restrict__ gbsh,
           u16* __restrict__ x1) {
    const int m0 = blockIdx.x * 8;
    __shared__ float sg[8][16];
    const int tid = threadIdx.x;
    const int row = tid >> 5, l = tid & 31;
    const long rb = m0 + row;

    float a[4] = {0,0,0,0}, b[4] = {0,0,0,0}, c[6] = {0,0,0,0,0,0};
    {
        const u16* er = embed + rb * 512 + l * 16;
        u16x8 xa = *(const u16x8*)(er);
        u16x8 xb = *(const u16x8*)(er + 8);
        #pragma unroll
        for (int u = 0; u < 16; u++) {
            int k = l * 16 + u;
            float xv = bf2f(u < 8 ? xa[u] : xb[u - 8]);
            float4 wa = *(const float4*)(g1Ws + k * 4);
            float4 wb = *(const float4*)(g1Ws + 2048 + k * 4);
            a[0] += xv * wa.x; a[1] += xv * wa.y; a[2] += xv * wa.z; a[3] += xv * wa.w;
            b[0] += xv * wb.x; b[1] += xv * wb.y; b[2] += xv * wb.z; b[3] += xv * wb.w;
            float2 w0 = *(const float2*)(gWsh + k * 6);
            float2 w1 = *(const float2*)(gWsh + k * 6 + 2);
            float2 w2 = *(const float2*)(gWsh + k * 6 + 4);
            c[0] += xv * w0.x; c[1] += xv * w0.y;
            c[2] += xv * w1.x; c[3] += xv * w1.y;
            c[4] += xv * w2.x; c[5] += xv * w2.y;
        }
    }
    #pragma unroll
    for (int off = 1; off < 32; off <<= 1) {
        #pragma unroll
        for (int g = 0; g < 4; g++) { a[g] += __shfl_xor(a[g], off); b[g] += __shfl_xor(b[g], off); }
        #pragma unroll
        for (int g = 0; g < 6; g++) c[g] += __shfl_xor(c[g], off);
    }
    if (l == 0) {
        float mx, s, e[6];
        mx = -1e30f;
        for (int g = 0; g < 4; g++) { a[g] += g1bs[g]; mx = fmaxf(mx, a[g]); }
        s = 0.f; for (int g = 0; g < 4; g++) { e[g] = __expf(a[g] - mx); s += e[g]; }
        for (int g = 0; g < 4; g++) sg[row][g] = e[g] / s;
        mx = -1e30f;
        for (int g = 0; g < 4; g++) { b[g] += g1bs[4 + g]; mx = fmaxf(mx, b[g]); }
        s = 0.f; for (int g = 0; g < 4; g++) { e[g] = __expf(b[g] - mx); s += e[g]; }
        for (int g = 0; g < 4; g++) sg[row][4 + g] = e[g] / s;
        mx = -1e30f;
        for (int g = 0; g < 6; g++) { c[g] += gbsh[g]; mx = fmaxf(mx, c[g]); }
        s = 0.f; for (int g = 0; g < 6; g++) { e[g] = __expf(c[g] - mx); s += e[g]; }
        for (int g = 0; g < 6; g++) sg[row][8 + g] = e[g] / s;
    }
    __syncthreads();

    const int c8 = l * 8;
    const u16* ob = out1 + rb * 256 + c8;
    u16x8 o[6];
    #pragma unroll
    for (int k = 0; k < 6; k++) o[k] = *(const u16x8*)(ob + (long)k * BATCH * 256);
    const float* g = sg[row];
    u16x8 r0, r1, r2;
    #pragma unroll
    for (int u = 0; u < 8; u++) {
        float o0 = bf2f(o[0][u]), o1 = bf2f(o[1][u]), o2 = bf2f(o[2][u]);
        float o3 = bf2f(o[3][u]), o4 = bf2f(o[4][u]), o5 = bf2f(o[5][u]);
        r0[u] = f2bf(g[0] * o0 + g[1] * o1 + g[2] * o4 + g[3] * o5);
        r1[u] = f2bf(g[4] * o2 + g[5] * o3 + g[6] * o4 + g[7] * o5);
        r2[u] = f2bf(g[8] * o0 + g[9] * o1 + g[10] * o2 + g[11] * o3 + g[12] * o4 + g[13] * o5);
    }
    *(u16x8*)(x1 + ((long)0 * BATCH + rb) * 256 + c8) = r0;
    *(u16x8*)(x1 + ((long)1 * BATCH + rb) * 256 + c8) = r1;
    *(u16x8*)(x1 + ((long)2 * BATCH + rb) * 256 + c8) = r2;
}

// ---------------------------------------------------------------------------
// Fused gate2 + towers: block = (64 batch rows, task t).
// Step 1: compute x2 slab in-LDS from o_buf2 + x1-logits (gate2, zero redundancy).
// Step 2: tower MLP (r7-P7-verified fragment paths, W direct from global).
// ---------------------------------------------------------------------------
__global__ __launch_bounds__(256, 2)
void tower_g2(const u16* __restrict__ x1, const u16* __restrict__ out2,
              const float* __restrict__ g2Ws, const float* __restrict__ g2bs,
              const u16* __restrict__ twW1t, const float* __restrict__ twb1,
              const u16* __restrict__ twW2t, const float* __restrict__ twb2,
              float* __restrict__ out) {
    const int t = blockIdx.y, m0 = blockIdx.x * 64;
    __shared__ u16 sX[64 * 256];     // x2 slab, chunk-swizzled
    __shared__ u16 sH[64 * 128];     // hidden, chunk-swizzled
    __shared__ float sg[64][4];
    const int tid = threadIdx.x, lane = tid & 63, w4 = tid >> 6;
    const int l16 = lane & 15, q = lane >> 4;

    // ---- gate2 logits for task t: 4 threads per row ----
    const int row = tid >> 2, p = tid & 3;
    {
        const u16* xr = x1 + ((long)t * BATCH + m0 + row) * 256 + p * 64;
        const float* W = g2Ws + t * 1024;
        float a[4] = {0, 0, 0, 0};
        #pragma unroll
        for (int j = 0; j < 8; j++) {
            u16x8 xv8 = *(const u16x8*)(xr + j * 8);
            #pragma unroll
            for (int u = 0; u < 8; u++) {
                int k = p * 64 + j * 8 + u;
                float4 wv = *(const float4*)(W + k * 4);
                float xv = bf2f(xv8[u]);
                a[0] += xv * wv.x; a[1] += xv * wv.y; a[2] += xv * wv.z; a[3] += xv * wv.w;
            }
        }
        #pragma unroll
        for (int g = 0; g < 4; g++) { a[g] += __shfl_xor(a[g], 1); a[g] += __shfl_xor(a[g], 2); }
        if (p == 0) {
            float mx = -1e30f, s = 0.f, e[4];
            for (int g = 0; g < 4; g++) { a[g] += g2bs[t * 4 + g]; mx = fmaxf(mx, a[g]); }
            for (int g = 0; g < 4; g++) { e[g] = __expf(a[g] - mx); s += e[g]; }
            for (int g = 0; g < 4; g++) sg[row][g] = e[g] / s;
        }
    }
    __syncthreads();

    // ---- combine -> sX (swizzled):  experts {2t, 2t+1, 4, 5} ----
    {
        const long rb = m0 + row;
        const float* g = sg[row];
        const u16* o0p = out2 + ((long)(2 * t)     * BATCH + rb) * 256 + p * 64;
        const u16* o1p = out2 + ((long)(2 * t + 1) * BATCH + rb) * 256 + p * 64;
        const u16* o4p = out2 + ((long)4           * BATCH + rb) * 256 + p * 64;
        const u16* o5p = out2 + ((long)5           * BATCH + rb) * 256 + p * 64;
        #pragma unroll
        for (int j = 0; j < 8; j++) {
            u16x8 v0 = *(const u16x8*)(o0p + j * 8);
            u16x8 v1 = *(const u16x8*)(o1p + j * 8);
            u16x8 v4 = *(const u16x8*)(o4p + j * 8);
            u16x8 v5 = *(const u16x8*)(o5p + j * 8);
            u16x8 r;
            #pragma unroll
            for (int u = 0; u < 8; u++)
                r[u] = f2bf(g[0] * bf2f(v0[u]) + g[1] * bf2f(v1[u]) +
                            g[2] * bf2f(v4[u]) + g[3] * bf2f(v5[u]));
            int c = p * 8 + j;                       // chunk index 0..31
            int pc = (c & ~7) | ((c & 7) ^ (row & 7));
            *(u16x8*)(&sX[row * 256 + pc * 8]) = r;
        }
    }
    __syncthreads();

    // ---- tower phase 1: H = relu(X @ W1 + b1) ----
    const u16* W1 = twW1t + (long)t * 128 * 256;
    const u16* W2 = twW2t + (long)t * 64 * 128;
    f32x4 acc1[4][2] = {};
    #pragma unroll
    for (int kk = 0; kk < 8; kk++) {
        s16x8 af[4], bf[2];
        #pragma unroll
        for (int nt = 0; nt < 2; nt++) {
            int nrow = w4 * 32 + nt * 16 + l16;
            bf[nt] = *(const s16x8*)(W1 + (long)nrow * 256 + kk * 32 + q * 8);
        }
        #pragma unroll
        for (int mt = 0; mt < 4; mt++) {
            int rrow = mt * 16 + l16;
            int cc = kk * 4 + q;
            int pc = (cc & ~7) | ((cc & 7) ^ (rrow & 7));
            af[mt] = *(const s16x8*)(&sX[rrow * 256 + pc * 8]);
        }
        #pragma unroll
        for (int mt = 0; mt < 4; mt++)
            #pragma unroll
            for (int nt = 0; nt < 2; nt++)
                acc1[mt][nt] = __builtin_amdgcn_mfma_f32_16x16x32_bf16(
                    bf[nt], af[mt], acc1[mt][nt], 0, 0, 0);
    }
    #pragma unroll
    for (int mt = 0; mt < 4; mt++) {
        int rrow = mt * 16 + l16;
        #pragma unroll
        for (int nt = 0; nt < 2; nt++) {
            int col = w4 * 32 + nt * 16 + q * 4;
            float4 bv = *(const float4*)(twb1 + t * 128 + col);
            f32x4 v = acc1[mt][nt];
            u16x4 o;
            o.x = f2bf(fmaxf(v.x + bv.x, 0.f));
            o.y = f2bf(fmaxf(v.y + bv.y, 0.f));
            o.z = f2bf(fmaxf(v.z + bv.z, 0.f));
            o.w = f2bf(fmaxf(v.w + bv.w, 0.f));
            int c = col >> 3;
            int pc = (c & ~7) | ((c & 7) ^ (rrow & 7));
            *(u16x4*)(&sH[rrow * 128 + pc * 8 + (col & 7)]) = o;
        }
    }
    __syncthreads();

    // ---- tower phase 2: out = sigmoid(H @ W2 + b2) ----
    f32x4 acc2[4] = {};
    #pragma unroll
    for (int kk = 0; kk < 4; kk++) {
        s16x8 af[4], bfv;
        {
            int nrow = w4 * 16 + l16;
            bfv = *(const s16x8*)(W2 + (long)nrow * 128 + kk * 32 + q * 8);
        }
        #pragma unroll
        for (int mt = 0; mt < 4; mt++) {
            int rrow = mt * 16 + l16;
            int cc = kk * 4 + q;
            int pc = (cc & ~7) | ((cc & 7) ^ (rrow & 7));
            af[mt] = *(const s16x8*)(&sH[rrow * 128 + pc * 8]);
        }
        #pragma unroll
        for (int mt = 0; mt < 4; mt++)
            acc2[mt] = __builtin_amdgcn_mfma_f32_16x16x32_bf16(
                bfv, af[mt], acc2[mt], 0, 0, 0);
    }
    #pragma unroll
    for (int mt = 0; mt < 4; mt++) {
        int grow = m0 + mt * 16 + l16;
        int col = w4 * 16 + q * 4;
        float4 bv = *(const float4*)(twb2 + t * 64 + col);
        f32x4 v = acc2[mt];
        float4 r;
        r.x = 1.f / (1.f + __expf(-(v.x + bv.x)));
        r.y = 1.f / (1.f + __expf(-(v.y + bv.y)));
        r.z = 1.f / (1.f + __expf(-(v.z + bv.z)));
        r.w = 1.f / (1.f + __expf(-(v.w + bv.w)));
        *(float4*)(out + (long)grow * 128 + t * 64 + col) = r;
    }
}

// ---------------------------------------------------------------------------
extern "C" void kernel_launch(void* const* d_in, const int* in_sizes, int n_in,
                              void* d_out, int out_size, void* d_ws, size_t ws_size,
                              hipStream_t stream) {
    const int*   x_ids = (const int*)  d_in[0];
    const float* emb   = (const float*)d_in[1];
    const float* e1W1  = (const float*)d_in[2];
    const float* e1b1  = (const float*)d_in[3];
    const float* e1W2  = (const float*)d_in[4];
    const float* e1b2  = (const float*)d_in[5];
    const float* g1Ws  = (const float*)d_in[6];
    const float* g1bs  = (const float*)d_in[7];
    const float* g1Wsh = (const float*)d_in[8];
    const float* g1bsh = (const float*)d_in[9];
    const float* e2W1  = (const float*)d_in[10];
    const float* e2b1  = (const float*)d_in[11];
    const float* e2W2  = (const float*)d_in[12];
    const float* e2b2  = (const float*)d_in[13];
    const float* g2Ws  = (const float*)d_in[14];
    const float* g2bs  = (const float*)d_in[15];
    const float* twW1  = (const float*)d_in[16];
    const float* twb1  = (const float*)d_in[17];
    const float* twW2  = (const float*)d_in[18];
    const float* twb2  = (const float*)d_in[19];
    float* out = (float*)d_out;

    char* ws = (char*)d_ws;
    u16* embed   = (u16*)(ws + 0);                       // [B,512]
    u16* wt_e1W1 = (u16*)(ws + 16777216);                // [6,512,512]
    u16* wt_e1W2 = (u16*)(ws + 19922944);                // [6,256,512]
    u16* wt_e2W1 = (u16*)(ws + 21495808);                // [6,512,256]
    u16* wt_e2W2 = (u16*)(ws + 23068672);                // [6,256,512]
    u16* wt_twW1 = (u16*)(ws + 24641536);                // [2,128,256]
    u16* wt_twW2 = (u16*)(ws + 24772608);                // [2,64,128]
    u16* h_buf   = (u16*)(ws + 24805376);                // [6,B,512]
    u16* o_buf   = (u16*)(ws + 125468672);               // [6,B,256]
    u16* x1      = (u16*)(ws + 175800320);               // [3,B,256]

    P0Args p0;
    p0.x_ids = x_ids; p0.emb = emb;
    p0.e1W1 = e1W1; p0.e1W2 = e1W2; p0.e2W1 = e2W1; p0.e2W2 = e2W2;
    p0.twW1 = twW1; p0.twW2 = twW2;
    p0.embed = embed; p0.wt_e1W1 = wt_e1W1; p0.wt_e1W2 = wt_e1W2;
    p0.wt_e2W1 = wt_e2W1; p0.wt_e2W2 = wt_e2W2;
    p0.wt_twW1 = wt_twW1; p0.wt_twW2 = wt_twW2;
    p0_gather_prep<<<dim3(512), 256, 0, stream>>>(p0);

    GemmP p1a = { embed, wt_e1W1, e1b1, h_buf, 512, 512, 3, 512, 0L, (long)BATCH * 512 };
    gemm_l1a<<<dim3(128, 2, 6), 256, 0, stream>>>(p1a);

    GemmP p1b = { h_buf, wt_e1W2, e1b2, o_buf, 256, 512, 0, 256,
                  (long)BATCH * 512, (long)BATCH * 256 };
    gemm_l1b<<<dim3(128, 1, 6), 256, 0, stream>>>(p1b);

    gate1<<<dim3(BATCH / 8), 256, 0, stream>>>(embed, o_buf, g1Ws, g1bs, g1Wsh, g1bsh, x1);

    GemmP p2a = { x1, wt_e2W1, e2b1, h_buf, 512, 256, 1, 512,
                  (long)BATCH * 256, (long)BATCH * 512 };
    gemm_l2a<<<dim3(128, 2, 6), 256, 0, stream>>>(p2a);

    GemmP p2b = { h_buf, wt_e2W2, e2b2, o_buf, 256, 512, 0, 256,
                  (long)BATCH * 512, (long)BATCH * 256 };
    gemm_l2b<<<dim3(128, 1, 6), 256, 0, stream>>>(p2b);

    tower_g2<<<dim3(BATCH / 64, 2), 256, 0, stream>>>(
        x1, o_buf, g2Ws, g2bs, wt_twW1, twb1, wt_twW2, twb2, out);
}